// Round 6
// baseline (330.664 us; speedup 1.0000x reference)
//
#include <hip/hip_runtime.h>

// Problem constants (reference: BATCH=64, NUM_SPEC=8, VOCAB=128000)
constexpr int BATCH    = 64;
constexpr int NUM_SPEC = 8;
constexpr int VOCAB    = 128000;
constexpr int ROWS     = BATCH * NUM_SPEC;   // 512 argmax rows
constexpr int NVEC     = VOCAB / 4;          // 32000 float4 per row
constexpr int T1       = 1024;               // threads per argmax block (16 waves)

// Native Clang vector type (maps to a 4-VGPR tuple).
typedef float vfloat4 __attribute__((ext_vector_type(4)));

// Fully cache-bypassing streaming load: sc0 sc1 nt = system-scope,
// non-temporal, no allocation. R2 showed a 178 MB dirty-writeback storm
// (harness 1 GB 0xAA ws-poison leaves LLC dirty; allocating reads force
// evictions). R5 confirmed bypass removes it (argmax ~157 -> ~78 us).
__device__ __forceinline__ void nt_load(vfloat4& dst, const vfloat4* addr) {
    asm volatile("global_load_dwordx4 %0, %1, off sc0 sc1 nt"
                 : "=v"(dst) : "v"(addr));
}
// Partial drain: wait until <=4 loads outstanding (i.e. the OLDER group of 4
// has returned; the 4 just-issued prefetch loads stay in flight).
__device__ __forceinline__ void wait_le4(vfloat4& a, vfloat4& b, vfloat4& c, vfloat4& d) {
    asm volatile("s_waitcnt vmcnt(4)"
                 : "+v"(a), "+v"(b), "+v"(c), "+v"(d));
}
__device__ __forceinline__ void wait_all(vfloat4& a, vfloat4& b, vfloat4& c, vfloat4& d) {
    asm volatile("s_waitcnt vmcnt(0)"
                 : "+v"(a), "+v"(b), "+v"(c), "+v"(d));
}

// Per-row argmax over vocab, first-index tie-break (matches jnp.argmax).
// One 1024-thread block per row. R6 change: software-pipelined double-buffer —
// issue group j+1, wait vmcnt(4) (drains only group j), consume group j.
// Each wave keeps 4-8 KB in flight continuously instead of sawtoothing to
// zero at a vmcnt(0) every group (R5's suspected residual limiter).
// No min-waves clamp: 2 live groups cost +32 VGPRs; forcing <=64 VGPR would
// spill, and R2 showed 16 vs 32 waves/CU is perf-neutral for this kernel.
__global__ __launch_bounds__(T1) void rs_argmax(const float* __restrict__ logits,
                                                int* __restrict__ targets) {
    const int row = blockIdx.x;  // 0..511
    const int tid = threadIdx.x;
    const vfloat4* __restrict__ rowp =
        reinterpret_cast<const vfloat4*>(logits + (size_t)row * VOCAB);

    float best = -__builtin_inff();
    int   bidx = VOCAB;  // sentinel

    auto upd = [&](const vfloat4 v, const int vecidx) {
        const int base = vecidx << 2;
        if (v.x > best) { best = v.x; bidx = base;     }
        if (v.y > best) { best = v.y; bidx = base + 1; }
        if (v.z > best) { best = v.z; bidx = base + 2; }
        if (v.w > best) { best = v.w; bidx = base + 3; }
    };

    // 8 groups of 4 strides: vec indices tid + k*1024, k = 0..31.
    // Group 7 (k=28..31): k=31 exists only for tid < 256 (tid+31744 < 32000);
    // clamp its address in-bounds for tid >= 256 and predicate the update.
    // Per-thread indices strictly increase, so '>' keeps lowest index on ties.
    const bool has4 = (tid < 256);
    vfloat4 b0[4], b1[4];

    // Prologue: issue group 0.
    nt_load(b0[0], rowp + tid);
    nt_load(b0[1], rowp + tid + 1024);
    nt_load(b0[2], rowp + tid + 2048);
    nt_load(b0[3], rowp + tid + 3072);

    #pragma unroll
    for (int j = 0; j < 7; ++j) {
        vfloat4* cur = (j & 1) ? b1 : b0;   // group j
        vfloat4* nxt = (j & 1) ? b0 : b1;   // group j+1
        const int in = tid + (j + 1) * 4096;
        nt_load(nxt[0], rowp + in);
        nt_load(nxt[1], rowp + in + 1024);
        nt_load(nxt[2], rowp + in + 2048);
        nt_load(nxt[3], (j == 6 && !has4) ? (rowp + in) : (rowp + in + 3072));
        wait_le4(cur[0], cur[1], cur[2], cur[3]);   // group j landed
        const int i = tid + j * 4096;
        upd(cur[0], i);
        upd(cur[1], i + 1024);
        upd(cur[2], i + 2048);
        upd(cur[3], i + 3072);
    }
    // Epilogue: consume group 7 (parity: 7 & 1 -> b1).
    wait_all(b1[0], b1[1], b1[2], b1[3]);
    {
        const int i = tid + 28672;
        upd(b1[0], i);
        upd(b1[1], i + 1024);
        upd(b1[2], i + 2048);
        if (has4) upd(b1[3], i + 3072);
    }

    // 64-lane wave reduction, lowest-index tie-break.
    #pragma unroll
    for (int off = 32; off > 0; off >>= 1) {
        const float ov = __shfl_down(best, off, 64);
        const int   oi = __shfl_down(bidx, off, 64);
        if (ov > best || (ov == best && oi < bidx)) { best = ov; bidx = oi; }
    }

    __shared__ float sval[T1 / 64];
    __shared__ int   sidx[T1 / 64];
    const int lane = tid & 63;
    const int wave = tid >> 6;
    if (lane == 0) { sval[wave] = best; sidx[wave] = bidx; }
    __syncthreads();

    if (tid == 0) {
        best = sval[0]; bidx = sidx[0];
        #pragma unroll
        for (int w = 1; w < T1 / 64; ++w) {
            if (sval[w] > best || (sval[w] == best && sidx[w] < bidx)) {
                best = sval[w]; bidx = sidx[w];
            }
        }
        targets[row] = bidx;
    }
}

// Per-batch rejection-sampling logic. One thread per batch row.
// Output layout (int32, concatenated flat in return order):
//   [0,   576)  output_token_ids [64,9]
//   [576, 640)  num_rejected_tokens [64]
//   [640, 704)  last_token_ids [64]
__global__ __launch_bounds__(64) void rs_finalize(const int* __restrict__ targets,
                                                  const int* __restrict__ draft,
                                                  const int* __restrict__ bonus,
                                                  int* __restrict__ out) {
    const int b = threadIdx.x;
    if (b >= BATCH) return;

    int tgt[NUM_SPEC];
    int L = 0;            // matched-prefix length
    bool prefix = true;
    #pragma unroll
    for (int s = 0; s < NUM_SPEC; ++s) {
        tgt[s] = targets[b * NUM_SPEC + s];
        const bool m = (draft[b * NUM_SPEC + s] == tgt[s]);
        prefix = prefix && m;
        if (prefix) ++L;
    }

    const bool all_acc = (L == NUM_SPEC);
    const int keep_cnt = all_acc ? NUM_SPEC : (L + 1);

    int* __restrict__ out_tok = out + b * (NUM_SPEC + 1);
    #pragma unroll
    for (int s = 0; s < NUM_SPEC; ++s) {
        out_tok[s] = (s < keep_cnt) ? tgt[s] : -1;
    }
    const int bonus_tok = bonus[b];
    out_tok[NUM_SPEC] = all_acc ? bonus_tok : -1;

    out[BATCH * (NUM_SPEC + 1) + b] = NUM_SPEC - L;                // num_rejected
    out[BATCH * (NUM_SPEC + 1) + BATCH + b] = all_acc ? bonus_tok  // last_token
                                                      : tgt[L];
}

extern "C" void kernel_launch(void* const* d_in, const int* in_sizes, int n_in,
                              void* d_out, int out_size, void* d_ws, size_t ws_size,
                              hipStream_t stream) {
    const float* logits = (const float*)d_in[0];  // [64, 8, 128000] fp32
    const int*   draft  = (const int*)d_in[1];    // [64, 8] int32
    const int*   bonus  = (const int*)d_in[2];    // [64, 1] int32
    int* out = (int*)d_out;                       // 704 int32
    int* targets = (int*)d_ws;                    // 512 int32 scratch

    rs_argmax<<<ROWS, T1, 0, stream>>>(logits, targets);
    rs_finalize<<<1, 64, 0, stream>>>(targets, draft, bonus, out);
}

// Round 7
// 328.756 us; speedup vs baseline: 1.0058x; 1.0058x over previous
//
#include <hip/hip_runtime.h>

// Problem constants (reference: BATCH=64, NUM_SPEC=8, VOCAB=128000)
constexpr int BATCH    = 64;
constexpr int NUM_SPEC = 8;
constexpr int VOCAB    = 128000;
constexpr int ROWS     = BATCH * NUM_SPEC;   // 512 argmax rows
constexpr int NVEC     = VOCAB / 4;          // 32000 float4 per row
constexpr int T1       = 1024;               // threads per argmax block (16 waves)

// Native Clang vector type (maps to a 4-VGPR tuple).
typedef float vfloat4 __attribute__((ext_vector_type(4)));

// Fully cache-bypassing streaming load: sc0 sc1 nt = bypass L1+L2, non-
// temporal. Session evidence:
//   R2 plain loads:   argmax ~157 us — 178 MB phantom WRITE_SIZE (dirty-line
//                     eviction storm from harness 0xAA poison + restore).
//   R4 nt only:       ~135 us — L2 still thrashes.
//   R5 sc0 sc1 nt:    ~78 us — L1/L2 fully bypassed. Remaining gap to the
//                     42 us clean-cache floor is memory-side MALL allocate-
//                     on-miss displacing dirty harness lines (~130-180 MB of
//                     forced writeback concurrent with our fetch) — no
//                     request-side knob exists for MALL allocation.
//   R6 SW pipelining (vmcnt(4) double-buffer): neutral (330.7 vs 326.5) —
//                     16 waves/CU already cover latency via TLP. Reverted.
__device__ __forceinline__ void nt_load(vfloat4& dst, const vfloat4* addr) {
    asm volatile("global_load_dwordx4 %0, %1, off sc0 sc1 nt"
                 : "=v"(dst) : "v"(addr));
}
// Asm loads are invisible to compiler vmcnt tracking: tie results to a drain.
__device__ __forceinline__ void wait4(vfloat4& a, vfloat4& b, vfloat4& c, vfloat4& d) {
    asm volatile("s_waitcnt vmcnt(0)"
                 : "+v"(a), "+v"(b), "+v"(c), "+v"(d));
}

// Per-row argmax over vocab, first-index tie-break (matches jnp.argmax).
// One 1024-thread block per row: 512 blocks -> 2 blocks/CU -> 32 waves/CU.
__global__ __launch_bounds__(T1, 8) void rs_argmax(const float* __restrict__ logits,
                                                   int* __restrict__ targets) {
    const int row = blockIdx.x;  // 0..511
    const int tid = threadIdx.x;
    const vfloat4* __restrict__ rowp =
        reinterpret_cast<const vfloat4*>(logits + (size_t)row * VOCAB);

    float best = -__builtin_inff();
    int   bidx = VOCAB;  // sentinel

    auto upd = [&](const vfloat4 v, const int vecidx) {
        const int base = vecidx << 2;
        if (v.x > best) { best = v.x; bidx = base;     }
        if (v.y > best) { best = v.y; bidx = base + 1; }
        if (v.z > best) { best = v.z; bidx = base + 2; }
        if (v.w > best) { best = v.w; bidx = base + 3; }
    };

    // 7 groups x 4 strides: vec indices tid + k*1024, k = 0..27.
    // Per-thread indices strictly increase, so '>' keeps lowest index on ties.
    #pragma unroll
    for (int j = 0; j < 7; ++j) {
        const int i = tid + j * 4096;
        vfloat4 v0, v1, v2, v3;
        nt_load(v0, rowp + i);
        nt_load(v1, rowp + i + 1024);
        nt_load(v2, rowp + i + 2048);
        nt_load(v3, rowp + i + 3072);
        wait4(v0, v1, v2, v3);
        upd(v0, i);
        upd(v1, i + 1024);
        upd(v2, i + 2048);
        upd(v3, i + 3072);
    }
    // Tail: k = 28,29,30 full; k = 31 exists only for tid < 256
    // (tid + 31744 < 32000). Clamp the address in-bounds for tid >= 256 and
    // predicate the update.
    {
        const int i = tid + 28672;
        const bool has4 = (tid < 256);
        const vfloat4* p3 = has4 ? (rowp + i + 3072) : (rowp + i);
        vfloat4 v0, v1, v2, v3;
        nt_load(v0, rowp + i);
        nt_load(v1, rowp + i + 1024);
        nt_load(v2, rowp + i + 2048);
        nt_load(v3, p3);
        wait4(v0, v1, v2, v3);
        upd(v0, i);
        upd(v1, i + 1024);
        upd(v2, i + 2048);
        if (has4) upd(v3, i + 3072);
    }

    // 64-lane wave reduction, lowest-index tie-break.
    #pragma unroll
    for (int off = 32; off > 0; off >>= 1) {
        const float ov = __shfl_down(best, off, 64);
        const int   oi = __shfl_down(bidx, off, 64);
        if (ov > best || (ov == best && oi < bidx)) { best = ov; bidx = oi; }
    }

    __shared__ float sval[T1 / 64];
    __shared__ int   sidx[T1 / 64];
    const int lane = tid & 63;
    const int wave = tid >> 6;
    if (lane == 0) { sval[wave] = best; sidx[wave] = bidx; }
    __syncthreads();

    if (tid == 0) {
        best = sval[0]; bidx = sidx[0];
        #pragma unroll
        for (int w = 1; w < T1 / 64; ++w) {
            if (sval[w] > best || (sval[w] == best && sidx[w] < bidx)) {
                best = sval[w]; bidx = sidx[w];
            }
        }
        targets[row] = bidx;
    }
}

// Per-batch rejection-sampling logic. One thread per batch row.
// Output layout (int32, concatenated flat in return order):
//   [0,   576)  output_token_ids [64,9]
//   [576, 640)  num_rejected_tokens [64]
//   [640, 704)  last_token_ids [64]
__global__ __launch_bounds__(64) void rs_finalize(const int* __restrict__ targets,
                                                  const int* __restrict__ draft,
                                                  const int* __restrict__ bonus,
                                                  int* __restrict__ out) {
    const int b = threadIdx.x;
    if (b >= BATCH) return;

    int tgt[NUM_SPEC];
    int L = 0;            // matched-prefix length
    bool prefix = true;
    #pragma unroll
    for (int s = 0; s < NUM_SPEC; ++s) {
        tgt[s] = targets[b * NUM_SPEC + s];
        const bool m = (draft[b * NUM_SPEC + s] == tgt[s]);
        prefix = prefix && m;
        if (prefix) ++L;
    }

    const bool all_acc = (L == NUM_SPEC);
    const int keep_cnt = all_acc ? NUM_SPEC : (L + 1);

    int* __restrict__ out_tok = out + b * (NUM_SPEC + 1);
    #pragma unroll
    for (int s = 0; s < NUM_SPEC; ++s) {
        out_tok[s] = (s < keep_cnt) ? tgt[s] : -1;
    }
    const int bonus_tok = bonus[b];
    out_tok[NUM_SPEC] = all_acc ? bonus_tok : -1;

    out[BATCH * (NUM_SPEC + 1) + b] = NUM_SPEC - L;                // num_rejected
    out[BATCH * (NUM_SPEC + 1) + BATCH + b] = all_acc ? bonus_tok  // last_token
                                                      : tgt[L];
}

extern "C" void kernel_launch(void* const* d_in, const int* in_sizes, int n_in,
                              void* d_out, int out_size, void* d_ws, size_t ws_size,
                              hipStream_t stream) {
    const float* logits = (const float*)d_in[0];  // [64, 8, 128000] fp32
    const int*   draft  = (const int*)d_in[1];    // [64, 8] int32
    const int*   bonus  = (const int*)d_in[2];    // [64, 1] int32
    int* out = (int*)d_out;                       // 704 int32
    int* targets = (int*)d_ws;                    // 512 int32 scratch

    rs_argmax<<<ROWS, T1, 0, stream>>>(logits, targets);
    rs_finalize<<<1, 64, 0, stream>>>(targets, draft, bonus, out);
}